// Round 8
// baseline (287.628 us; speedup 1.0000x reference)
//
#include <hip/hip_runtime.h>
#include <hip/hip_bf16.h>
#include <math.h>

// Problem constants
#define BGR 8        // graphs
#define PP 4096      // points per graph
#define NPTS 32768   // B*P
#define KNN 20
#define LCOV 10
#define FF 32
#define KS 5
#define NCLS 40
#define NGROUP 24    // 3*B, rows of ys
#define GROUPLEN 131072  // P*F flat elements per group

// KNN tiling: 256 blocks x 1024 threads; thread = (eighth 0..7, pt 0..127)
// -> 16 waves/block, 2 blocks/CU (48KB LDS), 32 waves/CU = max occupancy.
#define SPLIT 8
#define CHUNK (PP / SPLIT)        // 512 candidates per thread
#define PTSBLK 128                // points per block
#define KTHR 1024
#define CAP 4                     // per-lane candidate buffer (depth-4 FIFO)
#define NSLOT (KNN + 1)           // 21-slot network (self-point absorbable)
#define MPAD NSLOT                // merge-list stride 21: gcd(21,32)=1
#define SENT 0xFFFFFFFFu

// ---------------------------------------------------------------------------
// Kernel 1: brute-force KNN — PACKED-KEY top-k.
// R8 changes vs R7 (wave-coherence analysis: accept body + flush bill at
// wave rate; flush min/max chains are latency-bound at 4 waves/SIMD):
//  (a) 1024-thread blocks -> 8 waves/SIMD interleave the flush chains.
//  (b) reject test = raw d_bits < worstb (uint order == float order for
//      d>=0; SENT-safe). Key packed ONLY in the accept branch.
//  (c) cnt removed: flush trigger = __any(bufk[3] != SENT).
//  (d) merge in two 64-point phases (8*64*21 = 10752 words per phase fits
//      the 12288-word arena; 8*128*21 would not).
// ---------------------------------------------------------------------------
__device__ inline unsigned umn(unsigned a, unsigned b) { return a < b ? a : b; }
__device__ inline unsigned umx(unsigned a, unsigned b) { return a > b ? a : b; }

__global__ __launch_bounds__(KTHR, 8) void knn_kernel(const float* __restrict__ pos,
                                                      int* __restrict__ nbr) {
    __shared__ float smem[3 * PP];   // 48 KB arena
    float* sx = smem;
    float* sy = smem + PP;
    float* sz = smem + 2 * PP;

    int b = blockIdx.x >> 5;          // 32 blocks per graph
    int blkInGraph = blockIdx.x & 31;
    const float* gp = pos + (size_t)b * PP * 3;
    for (int i = threadIdx.x; i < PP; i += KTHR) {
        sx[i] = gp[i * 3 + 0];
        sy[i] = gp[i * 3 + 1];
        sz[i] = gp[i * 3 + 2];
    }
    __syncthreads();

    int eighth = threadIdx.x >> 7;        // 0..7 (wave-uniform)
    int pt = threadIdx.x & (PTSBLK - 1);  // 0..127
    int li = blkInGraph * PTSBLK + pt;    // local point index in graph
    float px = sx[li], py = sy[li], pz = sz[li];

    unsigned bd[NSLOT];
#pragma unroll
    for (int k = 0; k < NSLOT; k++) bd[k] = SENT;
    unsigned worstb = SENT;

    unsigned bufk[CAP];
#pragma unroll
    for (int s = 0; s < CAP; s++) bufk[s] = SENT;

    auto flush = [&]() {
#pragma unroll
        for (int s = 0; s < CAP; s++) {
            if (__any(bufk[s] != SENT)) {
                unsigned k = bufk[s];
#pragma unroll
                for (int i = 0; i < NSLOT; i++) {
                    unsigned lo = umn(k, bd[i]);   // v_min_u32
                    k = umx(k, bd[i]);             // v_max_u32
                    bd[i] = lo;
                }
            }
            bufk[s] = SENT;
        }
        worstb = bd[NSLOT - 1];
    };

    int jbeg = eighth * CHUNK;
    for (int jj = jbeg; jj < jbeg + CHUNK; jj += 4) {
        // wave-uniform candidate index -> b128 broadcast loads
        float4 xv = *(const float4*)(sx + jj);
        float4 yv = *(const float4*)(sy + jj);
        float4 zv = *(const float4*)(sz + jj);
        float xa[4] = {xv.x, xv.y, xv.z, xv.w};
        float ya[4] = {yv.x, yv.y, yv.z, yv.w};
        float za[4] = {zv.x, zv.y, zv.z, zv.w};
#pragma unroll
        for (int u = 0; u < 4; u++) {
            float dx = px - xa[u];
            float dy = py - ya[u];
            float dz = pz - za[u];
            float d = dx * dx;
            d = fmaf(dy, dy, d);
            d = fmaf(dz, dz, d);
            unsigned db = __float_as_uint(d);
            if (db < worstb) {     // raw-bits filter (pack deferred to accept)
                bufk[3] = bufk[2];
                bufk[2] = bufk[1];
                bufk[1] = bufk[0];
                bufk[0] = (db & 0xFFFFF000u) | (unsigned)(jj + u);
            }
            if (__any(bufk[3] != SENT)) flush();
        }
    }
    flush();

    // ---- 8-way merge, two 64-point phases (arena = 12288 words) ----
    __syncthreads();
    unsigned* mk = (unsigned*)smem;
    for (int h = 0; h < 2; h++) {
        if ((pt >> 6) == h) {
            int lpt = pt & 63;
#pragma unroll
            for (int k = 0; k < NSLOT; k++)
                mk[(eighth * 64 + lpt) * MPAD + k] = bd[k];
        }
        __syncthreads();
        if (threadIdx.x < 64) {
            int p = threadIdx.x;
            const unsigned* base = &mk[p * MPAD];
            int cur[SPLIT];
#pragma unroll
            for (int q = 0; q < SPLIT; q++) cur[q] = 0;
            int gi = b * PP + blkInGraph * PTSBLK + h * 64 + p;
            // 21 picks; pick 0 is provably the self key (d=0 -> key=li).
#pragma unroll
            for (int t = 0; t < NSLOT; t++) {
                unsigned v[SPLIT];
#pragma unroll
                for (int q = 0; q < SPLIT; q++)
                    v[q] = base[q * 64 * MPAD + cur[q]];
                unsigned m = v[0];
#pragma unroll
                for (int q = 1; q < SPLIT; q++) m = umn(m, v[q]);
                if (t > 0) nbr[gi * KNN + (t - 1)] = b * PP + (int)(m & 0xFFFu);
#pragma unroll
                for (int q = 0; q < SPLIT; q++) cur[q] += (v[q] == m);
            }
        }
        __syncthreads();
    }
}

// ---------------------------------------------------------------------------
// 3x3 helpers + power iteration (replicates reference arithmetic)
// ---------------------------------------------------------------------------
__device__ inline void mat3vec(const float M[9], const float v[3], float w[3]) {
    w[0] = M[0] * v[0] + M[1] * v[1] + M[2] * v[2];
    w[1] = M[3] * v[0] + M[4] * v[1] + M[5] * v[2];
    w[2] = M[6] * v[0] + M[7] * v[1] + M[8] * v[2];
}

__device__ inline float pi3(const float M[9], float v[3]) {
    v[0] = v[1] = v[2] = 0.57735026918962576f;  // 3^-0.5 as f32
#pragma unroll
    for (int it = 0; it < 5; ++it) {
        float w[3];
        mat3vec(M, v, w);
        float nrm = sqrtf(w[0] * w[0] + w[1] * w[1] + w[2] * w[2]) + 1e-12f;
        v[0] = w[0] / nrm;
        v[1] = w[1] / nrm;
        v[2] = w[2] / nrm;
    }
    float w[3];
    mat3vec(M, v, w);
    return v[0] * w[0] + v[1] * w[1] + v[2] * w[2];
}

// ---------------------------------------------------------------------------
// Kernel 2a: per-point eigen stage (256 x 128 fills all CUs).
// Writes v3 and prescaled rows R: spline coord v_c = c . R_c + 2.
// ---------------------------------------------------------------------------
__global__ __launch_bounds__(128) void eig_kernel(
    const float* __restrict__ pos, const int* __restrict__ nbr,
    float* __restrict__ Rbuf, float* __restrict__ v3out) {
    int n = blockIdx.x * 128 + threadIdx.x;
    float px = pos[n * 3 + 0], py = pos[n * 3 + 1], pz = pos[n * 3 + 2];

    float cx[KNN], cy[KNN], cz[KNN];
#pragma unroll
    for (int k = 0; k < KNN; k++) {
        int id = nbr[n * KNN + k];
        cx[k] = pos[id * 3 + 0] - px;
        cy[k] = pos[id * 3 + 1] - py;
        cz[k] = pos[id * 3 + 2] - pz;
    }

    float M[9] = {0.f, 0.f, 0.f, 0.f, 0.f, 0.f, 0.f, 0.f, 0.f};
#pragma unroll
    for (int m = 0; m < LCOV; m++) {
        M[0] += cx[m] * cx[m];
        M[1] += cx[m] * cy[m];
        M[2] += cx[m] * cz[m];
        M[4] += cy[m] * cy[m];
        M[5] += cy[m] * cz[m];
        M[8] += cz[m] * cz[m];
    }
    M[3] = M[1];
    M[6] = M[2];
    M[7] = M[5];

    float v1[3], v2[3], v3[3];
    float l1 = pi3(M, v1);
    float M2[9];
#pragma unroll
    for (int c = 0; c < 3; c++)
#pragma unroll
        for (int d = 0; d < 3; d++) M2[c * 3 + d] = M[c * 3 + d] - l1 * v1[c] * v1[d];
    pi3(M2, v2);
    v3[0] = v1[1] * v2[2] - v1[2] * v2[1];
    v3[1] = v1[2] * v2[0] - v1[0] * v2[2];
    v3[2] = v1[0] * v2[1] - v1[1] * v2[0];
    {
        float nrm = sqrtf(v3[0] * v3[0] + v3[1] * v3[1] + v3[2] * v3[2]) + 1e-12f;
        v3[0] /= nrm;
        v3[1] /= nrm;
        v3[2] /= nrm;
    }

    float ssum = 0.f, mx = 0.f;
#pragma unroll
    for (int k = 0; k < KNN; k++) {
        float d0 = cx[k] * v1[0] + cy[k] * v1[1] + cz[k] * v1[2];
        float d1 = cx[k] * v2[0] + cy[k] * v2[1] + cz[k] * v2[2];
        float d2 = cx[k] * v3[0] + cy[k] * v3[1] + cz[k] * v3[2];
        ssum += d2;
        mx = fmaxf(mx, fabsf(d0));
        mx = fmaxf(mx, fabsf(d1));
        mx = fmaxf(mx, fabsf(d2));
    }
    float sgn = (ssum > 0.f) ? 1.f : ((ssum < 0.f) ? -1.f : 0.f);

    float sc = 2.0f / mx;
    float* R = Rbuf + (size_t)n * 12;
    R[0] = v1[0] * sc;  R[1] = v1[1] * sc;  R[2] = v1[2] * sc;
    R[3] = v2[0] * sc;  R[4] = v2[1] * sc;  R[5] = v2[2] * sc;
    float s2 = sgn * sc;
    R[6] = v3[0] * s2;  R[7] = v3[1] * s2;  R[8] = v3[2] * s2;
    R[9] = 0.f; R[10] = 0.f; R[11] = 0.f;

    v3out[n * 3 + 0] = v3[0];
    v3out[n * 3 + 1] = v3[1];
    v3out[n * 3 + 2] = v3[2];
}

// ---------------------------------------------------------------------------
// Kernel 2b: spline conv. Block = 512 threads = 16 points. (unchanged R7)
// ---------------------------------------------------------------------------
#define NPB 16
__global__ __launch_bounds__(512) void spline_kernel(
    const float* __restrict__ pos, const int* __restrict__ nbr,
    const float* __restrict__ Rbuf, const float* __restrict__ Wsp,
    const float* __restrict__ root, const float* __restrict__ bias,
    float* __restrict__ node) {
    __shared__ float sWt[FF * 125];          // [f][flat]
    __shared__ float wbuf[NPB * KNN * 8];    // packed w' per (pt,k,s)
    for (int i = threadIdx.x; i < FF * 125; i += 512) {
        int f = i / 125;
        int j = i - f * 125;
        sWt[i] = Wsp[j * FF + f];
    }

    int tid = threadIdx.x;
    if (tid < NPB * KNN) {              // 320 phase-1 threads
        int pt = tid / KNN;
        int k = tid - pt * KNN;
        int n = blockIdx.x * NPB + pt;
        const float4* Rv = (const float4*)(Rbuf + (size_t)n * 12);
        float4 r0 = Rv[0], r1 = Rv[1], r2 = Rv[2];
        float px = pos[n * 3 + 0], py = pos[n * 3 + 1], pz = pos[n * 3 + 2];
        int id = nbr[n * KNN + k];
        float cxx = pos[id * 3 + 0] - px;
        float cyy = pos[id * 3 + 1] - py;
        float czz = pos[id * 3 + 2] - pz;
        float v0 = fmaf(cxx, r0.x, fmaf(cyy, r0.y, fmaf(czz, r0.z, 2.0f)));
        float v1 = fmaf(cxx, r0.w, fmaf(cyy, r1.x, fmaf(czz, r1.y, 2.0f)));
        float v2 = fmaf(cxx, r1.z, fmaf(cyy, r1.w, fmaf(czz, r2.x, 2.0f)));
        float f0 = floorf(v0), f1 = floorf(v1), f2 = floorf(v2);
        float fr0 = v0 - f0, fr1 = v1 - f1, fr2 = v2 - f2;
        int fi0 = (int)f0, fi1 = (int)f1, fi2 = (int)f2;
        float* wdst = &wbuf[(pt * KNN + k) * 8];
#pragma unroll
        for (int s = 0; s < 8; s++) {
            int b0 = (s >> 2) & 1, b1 = (s >> 1) & 1, b2s = s & 1;
            int i0 = min(max(fi0 + b0, 0), KS - 1);
            int i1 = min(max(fi1 + b1, 0), KS - 1);
            int i2 = min(max(fi2 + b2s, 0), KS - 1);
            float w = (b0 ? fr0 : 1.f - fr0) * (b1 ? fr1 : 1.f - fr1) *
                      (b2s ? fr2 : 1.f - fr2);
            unsigned flat = (unsigned)((i0 * KS + i1) * KS + i2);
            wdst[s] = __uint_as_float((__float_as_uint(w) & ~127u) | flat);
        }
    }
    __syncthreads();

    // phase 2: thread = (pt, f)
    int pt = tid >> 5;
    int f = tid & 31;
    const float* wrow = &wbuf[pt * (KNN * 8)];
    const float* srow = &sWt[f * 125];
    float acc = 0.f;
#pragma unroll
    for (int k = 0; k < KNN; k++) {
        float4 wa = *(const float4*)&wrow[k * 8];
        float4 wb = *(const float4*)&wrow[k * 8 + 4];
        float wv[8] = {wa.x, wa.y, wa.z, wa.w, wb.x, wb.y, wb.z, wb.w};
#pragma unroll
        for (int s = 0; s < 8; s++) {
            unsigned u = __float_as_uint(wv[s]) & 127u;
            acc = fmaf(wv[s], srow[u], acc);
        }
    }
    int n = blockIdx.x * NPB + pt;
    node[(size_t)n * FF + f] = acc * (1.0f / KNN) + root[f] + bias[f];
}

// ---------------------------------------------------------------------------
// Kernel 3: batch-norm statistics — per-block PARTIALS (no atomics, no
// memset dependency). sums_part[block][0..31]=sum, [32..63]=sumsq.
// ---------------------------------------------------------------------------
#define BNBLK 128
__global__ __launch_bounds__(256) void bn_stats_kernel(const float* __restrict__ node,
                                                       float* __restrict__ sums_part) {
    __shared__ float ls[256];
    __shared__ float ls2[256];
    float s = 0.f, s2 = 0.f;
    int total = NPTS * FF;
    for (int i = blockIdx.x * 256 + threadIdx.x; i < total; i += BNBLK * 256) {
        float x = node[i];
        s += x;
        s2 += x * x;
    }
    ls[threadIdx.x] = s;
    ls2[threadIdx.x] = s2;
    __syncthreads();
    if (threadIdx.x < FF) {
        float a = 0.f, bb = 0.f;
        for (int t = threadIdx.x; t < 256; t += FF) {
            a += ls[t];
            bb += ls2[t];
        }
        sums_part[blockIdx.x * 64 + threadIdx.x] = a;
        sums_part[blockIdx.x * 64 + FF + threadIdx.x] = bb;
    }
}

// ---------------------------------------------------------------------------
// Kernel 4: apply BN, scale normal, sigmoid, reduce to ys partials.
// Each block reduces the 128 bn partials for its stats, then writes its
// p-range partial to ys_part[sub][g][f] (no atomics).
// ---------------------------------------------------------------------------
#define YSPLIT 8
#define YCHUNK (GROUPLEN / YSPLIT)   // 16384
__global__ __launch_bounds__(256) void ys_kernel(
    const float* __restrict__ node, const float* __restrict__ v3,
    const float* __restrict__ sums_part, const float* __restrict__ gamma,
    const float* __restrict__ beta, float* __restrict__ ys_part) {
    __shared__ float stat[64];
    __shared__ float sa[FF], sb[FF];
    if (threadIdx.x < 64) {
        float s = 0.f;
        for (int p2 = 0; p2 < BNBLK; p2++) s += sums_part[p2 * 64 + threadIdx.x];
        stat[threadIdx.x] = s;
    }
    __syncthreads();
    if (threadIdx.x < FF) {
        int f = threadIdx.x;
        float mu = stat[f] * (1.0f / NPTS);
        float var = stat[FF + f] * (1.0f / NPTS) - mu * mu;
        float inv = 1.0f / sqrtf(var + 1e-5f);
        sa[f] = gamma[f] * inv;
        sb[f] = beta[f] - gamma[f] * inv * mu;
    }
    __syncthreads();

    int g = blockIdx.x >> 3;
    int sub = blockIdx.x & 7;
    float acc = 0.f;
    int ibeg = sub * YCHUNK + threadIdx.x;
    int iend = (sub + 1) * YCHUNK;
    for (int i = ibeg; i < iend; i += 256) {
        int t = g * GROUPLEN + i;
        int n = t / 96;
        int r = t - n * 96;
        int f = r / 3;
        int c = r - f * 3;
        float xb = sa[f] * node[(size_t)n * FF + f] + sb[f];
        float val = xb * v3[n * 3 + c];
        acc += 1.0f / (1.0f + expf(-val));
    }
    __shared__ float red[256];
    red[threadIdx.x] = acc;
    __syncthreads();
    if (threadIdx.x < FF) {
        float s = 0.f;
        for (int t = threadIdx.x; t < 256; t += FF) s += red[t];
        ys_part[(sub * NGROUP + g) * FF + threadIdx.x] = s * (1.0f / PP);
    }
}

// ---------------------------------------------------------------------------
// Kernel 5: MLP head; sums the 8 ys partials while loading syr.
// ---------------------------------------------------------------------------
__global__ __launch_bounds__(256) void head_kernel(
    const float* __restrict__ ys_part, const float* __restrict__ W1,
    const float* __restrict__ b1, const float* __restrict__ W2,
    const float* __restrict__ b2, float* __restrict__ out) {
    int g = blockIdx.x;
    __shared__ float syr[FF];
    __shared__ float h[256];
    __shared__ float logits[NCLS];
    __shared__ float mstat[2];
    if (threadIdx.x < FF) {
        float s = 0.f;
#pragma unroll
        for (int sub = 0; sub < YSPLIT; sub++)
            s += ys_part[(sub * NGROUP + g) * FF + threadIdx.x];
        syr[threadIdx.x] = s;
    }
    __syncthreads();
    int j = threadIdx.x;
    float acc = b1[j];
#pragma unroll
    for (int f = 0; f < FF; f++) acc += syr[f] * W1[f * 256 + j];
    h[j] = acc > 0.f ? acc : expm1f(acc);
    __syncthreads();
    if (j < NCLS) {
        float l = b2[j];
        for (int q = 0; q < 256; q++) l += h[q] * W2[q * NCLS + j];
        logits[j] = l;
    }
    __syncthreads();
    if (j == 0) {
        float m = -INFINITY;
        for (int o = 0; o < NCLS; o++) m = fmaxf(m, logits[o]);
        float s = 0.f;
        for (int o = 0; o < NCLS; o++) s += expf(logits[o] - m);
        mstat[0] = m;
        mstat[1] = logf(s);
    }
    __syncthreads();
    if (j < NCLS) out[g * NCLS + j] = logits[j] - mstat[0] - mstat[1];
}

// ---------------------------------------------------------------------------
extern "C" void kernel_launch(void* const* d_in, const int* in_sizes, int n_in,
                              void* d_out, int out_size, void* d_ws, size_t ws_size,
                              hipStream_t stream) {
    const float* pos   = (const float*)d_in[0];
    const float* Wsp   = (const float*)d_in[1];
    const float* root  = (const float*)d_in[2];
    const float* bias  = (const float*)d_in[3];
    const float* gamma = (const float*)d_in[4];
    const float* beta  = (const float*)d_in[5];
    const float* W1    = (const float*)d_in[6];
    const float* b1    = (const float*)d_in[7];
    const float* W2    = (const float*)d_in[8];
    const float* b2    = (const float*)d_in[9];
    float* out = (float*)d_out;

    char* ws = (char*)d_ws;
    int* nbr    = (int*)(ws);                      // 32768*20*4   = 2621440 B
    float* node = (float*)(ws + 2621440);          // 32768*32*4   = 4194304 B
    float* v3   = (float*)(ws + 6815744);          // 32768*3*4    = 393216 B
    float* Rbuf = (float*)(ws + 7212288);          // 32768*12*4   = 1572864 B
    // bn/ys partials ALIAS the nbr region: nbr is dead after spline_kernel,
    // and bn_stats/ys run after it on the same stream. Zero ws growth.
    float* sums_part = (float*)(ws);               // 128*64*4 = 32768 B
    float* ys_part   = (float*)(ws + 32768);       // 8*24*32*4 = 24576 B

    knn_kernel<<<256, KTHR, 0, stream>>>(pos, nbr);
    eig_kernel<<<256, 128, 0, stream>>>(pos, nbr, Rbuf, v3);
    spline_kernel<<<NPTS / NPB, 512, 0, stream>>>(pos, nbr, Rbuf, Wsp, root, bias, node);
    bn_stats_kernel<<<BNBLK, 256, 0, stream>>>(node, sums_part);
    ys_kernel<<<NGROUP * YSPLIT, 256, 0, stream>>>(node, v3, sums_part, gamma, beta, ys_part);
    head_kernel<<<NGROUP, 256, 0, stream>>>(ys_part, W1, b1, W2, b2, out);
}